// Round 1
// baseline (814.982 us; speedup 1.0000x reference)
//
#include <hip/hip_runtime.h>
#include <hip/hip_bf16.h>
#include <cstdint>

#define B_   256
#define L_   196
#define ENC_ 2048
#define DEC_ 512
#define ATT_ 512
#define M_TOT (B_*L_)   // 50176, divisible by 64

typedef short short8 __attribute__((ext_vector_type(8)));
typedef float f32x16 __attribute__((ext_vector_type(16)));

__device__ __forceinline__ unsigned short f2bf(float f) {
    union { float f; unsigned u; } v; v.f = f;
    unsigned u = v.u;
    return (unsigned short)((u + 0x7FFFu + ((u >> 16) & 1u)) >> 16);  // RNE
}

__device__ __forceinline__ void gl_lds16(const void* g, void* l) {
    __builtin_amdgcn_global_load_lds((const __attribute__((address_space(1))) unsigned int*)g,
                                     (__attribute__((address_space(3))) unsigned int*)l,
                                     16, 0, 0);
}

// ---------- K0a: W_enc [ENC][ATT] fp32 -> WT [ATT][ENC] bf16 (transpose+convert) ----------
__global__ void k_transpose(const float* __restrict__ W, unsigned short* __restrict__ WT) {
    __shared__ float S[32*33];
    const int k0 = blockIdx.x * 32, n0 = blockIdx.y * 32;
    const int t  = threadIdx.x;
    const int c31 = t & 31, q = t >> 5;   // q = 0..7
#pragma unroll
    for (int i = 0; i < 4; ++i) {
        int kl = q + i*8;
        S[c31*33 + kl] = W[(size_t)(k0+kl)*ATT_ + n0 + c31];   // coalesced along n
    }
    __syncthreads();
#pragma unroll
    for (int i = 0; i < 4; ++i) {
        int nn = q + i*8;
        WT[(size_t)(n0+nn)*ENC_ + k0 + c31] = f2bf(S[nn*33 + c31]);  // coalesced along k
    }
}

// ---------- K0b: att2c[b][n] = h[b]@W_dec + b_dec + b_enc ; gate[b] = sigmoid(h@W_beta+b_beta) ----------
__global__ void k_prep2(const float* __restrict__ h, const float* __restrict__ Wdec,
                        const float* __restrict__ bdec, const float* __restrict__ benc,
                        const float* __restrict__ Wbeta, const float* __restrict__ bbeta,
                        float* __restrict__ att2c, float* __restrict__ gate) {
    const int b = blockIdx.x, t = threadIdx.x;   // 256 threads
    __shared__ float hs[DEC_];
    __shared__ float pr[4];
    hs[t]       = h[(size_t)b*DEC_ + t];
    hs[t + 256] = h[(size_t)b*DEC_ + t + 256];
    __syncthreads();
    float a0 = 0.f, a1 = 0.f;
    for (int k = 0; k < DEC_; ++k) {
        float hk = hs[k];
        a0 = fmaf(hk, Wdec[(size_t)k*ATT_ + t],       a0);
        a1 = fmaf(hk, Wdec[(size_t)k*ATT_ + t + 256], a1);
    }
    att2c[(size_t)b*ATT_ + t]       = a0 + bdec[t]       + benc[t];
    att2c[(size_t)b*ATT_ + t + 256] = a1 + bdec[t + 256] + benc[t + 256];
    float p = hs[t]*Wbeta[t] + hs[t+256]*Wbeta[t+256];
#pragma unroll
    for (int mask = 32; mask; mask >>= 1) p += __shfl_xor(p, mask, 64);
    if ((t & 63) == 0) pr[t >> 6] = p;
    __syncthreads();
    if (t == 0) gate[b] = 1.f / (1.f + __expf(-(pr[0]+pr[1]+pr[2]+pr[3] + bbeta[0])));
}

// ---------- K1: att[m] = sum_n relu(x[m]@W_enc[:,n] + att2c[b(m)][n]) * W_full[n] ----------
// Block: 64 rows x full N=512, 512 threads = 8 waves, wave tile 64x64, mfma_f32_32x32x16_bf16.
// LDS chunk-swizzle: chunk(r,kc) = r*4 + (kc ^ ((r>>1)&3)); 16B chunks -> conflict-free b128 reads
// and compatible with global_load_lds linear lane->chunk mapping.
__global__ __launch_bounds__(512, 4) void k_gemm(
        const float* __restrict__ x, const unsigned short* __restrict__ WT,
        const float* __restrict__ att2c, const float* __restrict__ Wfull,
        float* __restrict__ att) {
    __shared__ unsigned short Abuf[64*32];    // 4 KB  (64 rows x BK=32, swizzled)
    __shared__ unsigned short Bbuf[512*32];   // 32 KB (512 n x BK=32, swizzled)
    __shared__ float att_ws[8][64];

    const int tid   = threadIdx.x;
    const int wave  = tid >> 6;
    const int lane  = tid & 63;
    const int lane31 = lane & 31;
    const int laneh  = lane >> 5;
    const int m0 = blockIdx.x * 64;

    f32x16 acc[2][2];
#pragma unroll
    for (int i = 0; i < 2; ++i)
#pragma unroll
        for (int j = 0; j < 2; ++j)
#pragma unroll
            for (int r = 0; r < 16; ++r) acc[i][j][r] = 0.f;

    // A staging indices (fixed over k-loop): thread -> (row, 4-float group)
    const int ar   = tid >> 3;       // 0..63
    const int ak4  = tid & 7;        // 0..7  (4 floats each)
    const int akc  = ak4 >> 1;
    const int ahalf= ak4 & 1;
    const int achunk = ar*4 + (akc ^ ((ar >> 1) & 3));
    const float* xrow = x + (size_t)(m0 + ar)*ENC_ + ak4*4;
    unsigned short* adst = Abuf + achunk*8 + ahalf*4;

    for (int k0 = 0; k0 < ENC_; k0 += 32) {
        // B: 4 x global_load_lds (16B) per wave, direct to swizzled LDS
#pragma unroll
        for (int i = 0; i < 4; ++i) {
            int c  = wave*256 + i*64 + lane;
            int n  = c >> 2;
            int kc = (c & 3) ^ ((n >> 1) & 3);
            gl_lds16(WT + (size_t)n*ENC_ + k0 + kc*8,
                     (void*)(Bbuf + (wave*256 + i*64)*8));
        }
        // A: fp32 load -> bf16 -> swizzled ds_write (8B per thread)
        float4 xa = *(const float4*)(xrow + k0);
        ushort4 pk;
        pk.x = f2bf(xa.x); pk.y = f2bf(xa.y); pk.z = f2bf(xa.z); pk.w = f2bf(xa.w);
        *(ushort4*)adst = pk;
        __syncthreads();

#pragma unroll
        for (int ks = 0; ks < 2; ++ks) {
            short8 a[2], bfr[2];
#pragma unroll
            for (int mi = 0; mi < 2; ++mi) {
                int m = mi*32 + lane31;
                int chunk = m*4 + ((ks*2 + laneh) ^ ((m >> 1) & 3));
                a[mi] = *(const short8*)(Abuf + chunk*8);
            }
#pragma unroll
            for (int ni = 0; ni < 2; ++ni) {
                int n = wave*64 + ni*32 + lane31;
                int chunk = n*4 + ((ks*2 + laneh) ^ ((n >> 1) & 3));
                bfr[ni] = *(const short8*)(Bbuf + chunk*8);
            }
#pragma unroll
            for (int mi = 0; mi < 2; ++mi)
#pragma unroll
                for (int ni = 0; ni < 2; ++ni)
                    acc[mi][ni] = __builtin_amdgcn_mfma_f32_32x32x16_bf16(
                                      a[mi], bfr[ni], acc[mi][ni], 0, 0, 0);
        }
        __syncthreads();
    }

    // Epilogue: relu(acc + att2c[b][n]) * Wfull[n], reduce over n (512 in-block), write att[m].
    float* epi = (float*)Bbuf;  // [0..511]=Wfull, [512..1023]=att2c[b0], [1024..1535]=att2c[b1]
    {
        const int b0i = m0 / L_;
        const int b1i = (m0 + 63) / L_;
        epi[tid]        = Wfull[tid];
        epi[512 + tid]  = att2c[(size_t)b0i*ATT_ + tid];
        epi[1024 + tid] = att2c[(size_t)b1i*ATT_ + tid];
    }
    __syncthreads();
    const int split = (m0 / L_ + 1) * L_;   // first global row of b1
    const int n0 = wave*64 + lane31;
#pragma unroll
    for (int mi = 0; mi < 2; ++mi) {
#pragma unroll
        for (int reg = 0; reg < 16; ++reg) {
            int mloc = mi*32 + (reg & 3) + 8*(reg >> 2) + 4*laneh;  // verified C/D map (m74/m101)
            int off  = (m0 + mloc >= split) ? 1024 : 512;
            float v0 = acc[mi][0][reg] + epi[off + n0];
            float v1 = acc[mi][1][reg] + epi[off + n0 + 32];
            v0 = fmaxf(v0, 0.f) * epi[n0];
            v1 = fmaxf(v1, 0.f) * epi[n0 + 32];
            float s = v0 + v1;
#pragma unroll
            for (int mask = 16; mask; mask >>= 1) s += __shfl_xor(s, mask, 64);
            if (lane31 == 0) att_ws[wave][mloc] = s;
        }
    }
    __syncthreads();
    if (tid < 64) {
        float r = 0.f;
#pragma unroll
        for (int w = 0; w < 8; ++w) r += att_ws[w][tid];
        att[m0 + tid] = r;
    }
}

// ---------- K2: softmax over L, z = alpha@x[b], out0 = gate*z, out1 = alpha ----------
__global__ __launch_bounds__(512) void k_softz(
        const float* __restrict__ att, const float* __restrict__ x,
        const float* __restrict__ gate, float* __restrict__ out) {
    const int b = blockIdx.x, t = threadIdx.x;   // 512 threads
    __shared__ float sa[L_];
    __shared__ float red[16];
    const int wid = t >> 6, lane = t & 63;
    float v = (t < L_) ? att[b*L_ + t] : -1e30f;
    float m = v;
#pragma unroll
    for (int mask = 32; mask; mask >>= 1) m = fmaxf(m, __shfl_xor(m, mask, 64));
    if (lane == 0) red[wid] = m;
    __syncthreads();
    m = red[0];
#pragma unroll
    for (int w = 1; w < 8; ++w) m = fmaxf(m, red[w]);
    float e = (t < L_) ? __expf(v - m) : 0.f;
    float s = e;
#pragma unroll
    for (int mask = 32; mask; mask >>= 1) s += __shfl_xor(s, mask, 64);
    if (lane == 0) red[8 + wid] = s;
    __syncthreads();
    s = 0.f;
#pragma unroll
    for (int w = 0; w < 8; ++w) s += red[8 + w];
    float alpha = e / s;
    if (t < L_) { sa[t] = alpha; out[(size_t)B_*ENC_ + (size_t)b*L_ + t] = alpha; }
    __syncthreads();
    const float* xb = x + (size_t)b*L_*ENC_ + t*4;
    float4 z = {0.f, 0.f, 0.f, 0.f};
#pragma unroll 4
    for (int l = 0; l < L_; ++l) {
        float a = sa[l];
        float4 u = *(const float4*)(xb + (size_t)l*ENC_);
        z.x += a*u.x; z.y += a*u.y; z.z += a*u.z; z.w += a*u.w;
    }
    const float g = gate[b];
    float4 o; o.x = g*z.x; o.y = g*z.y; o.z = g*z.z; o.w = g*z.w;
    *(float4*)(out + (size_t)b*ENC_ + t*4) = o;
}

extern "C" void kernel_launch(void* const* d_in, const int* in_sizes, int n_in,
                              void* d_out, int out_size, void* d_ws, size_t ws_size,
                              hipStream_t stream) {
    const float* x      = (const float*)d_in[0];
    const float* h      = (const float*)d_in[1];
    const float* W_enc  = (const float*)d_in[2];
    const float* b_enc  = (const float*)d_in[3];
    const float* W_dec  = (const float*)d_in[4];
    const float* b_dec  = (const float*)d_in[5];
    const float* W_full = (const float*)d_in[6];
    // d_in[7] = b_full: softmax is shift-invariant -> unused
    const float* W_beta = (const float*)d_in[8];
    const float* b_beta = (const float*)d_in[9];
    float* out = (float*)d_out;

    char* ws = (char*)d_ws;
    unsigned short* WT = (unsigned short*)ws;                              // 2 MB
    float* att2c  = (float*)(ws + 2*1024*1024);                            // 512 KB
    float* gate   = (float*)(ws + 2*1024*1024 + 512*1024);                 // 1 KB
    float* attbuf = (float*)(ws + 2*1024*1024 + 512*1024 + 1024);          // 200 KB

    k_transpose<<<dim3(ENC_/32, ATT_/32), 256, 0, stream>>>(W_enc, WT);
    k_prep2   <<<B_, 256, 0, stream>>>(h, W_dec, b_dec, b_enc, W_beta, b_beta, att2c, gate);
    k_gemm    <<<M_TOT/64, 512, 0, stream>>>(x, WT, att2c, W_full, attbuf);
    k_softz   <<<B_, 512, 0, stream>>>(attbuf, x, gate, out);
}

// Round 2
// 772.130 us; speedup vs baseline: 1.0555x; 1.0555x over previous
//
#include <hip/hip_runtime.h>
#include <hip/hip_bf16.h>
#include <cstdint>

#define B_   256
#define L_   196
#define ENC_ 2048
#define DEC_ 512
#define ATT_ 512
#define M_TOT (B_*L_)   // 50176, divisible by 64

typedef short short8 __attribute__((ext_vector_type(8)));
typedef float f32x16 __attribute__((ext_vector_type(16)));

__device__ __forceinline__ unsigned short f2bf(float f) {
    union { float f; unsigned u; } v; v.f = f;
    unsigned u = v.u;
    return (unsigned short)((u + 0x7FFFu + ((u >> 16) & 1u)) >> 16);  // RNE
}

__device__ __forceinline__ void gl_lds16(const void* g, void* l) {
    __builtin_amdgcn_global_load_lds((const __attribute__((address_space(1))) unsigned int*)g,
                                     (__attribute__((address_space(3))) unsigned int*)l,
                                     16, 0, 0);
}

// ---------- K0a: W_enc [ENC][ATT] fp32 -> WT [ATT][ENC] bf16 (transpose+convert) ----------
__global__ void k_transpose(const float* __restrict__ W, unsigned short* __restrict__ WT) {
    __shared__ float S[32*33];
    const int k0 = blockIdx.x * 32, n0 = blockIdx.y * 32;
    const int t  = threadIdx.x;
    const int c31 = t & 31, q = t >> 5;   // q = 0..7
#pragma unroll
    for (int i = 0; i < 4; ++i) {
        int kl = q + i*8;
        S[c31*33 + kl] = W[(size_t)(k0+kl)*ATT_ + n0 + c31];   // coalesced along n
    }
    __syncthreads();
#pragma unroll
    for (int i = 0; i < 4; ++i) {
        int nn = q + i*8;
        WT[(size_t)(n0+nn)*ENC_ + k0 + c31] = f2bf(S[nn*33 + c31]);  // coalesced along k
    }
}

// ---------- K0b: att2c[b][n] = h[b]@W_dec + b_dec + b_enc ; gate[b] = sigmoid(h@W_beta+b_beta) ----------
__global__ void k_prep2(const float* __restrict__ h, const float* __restrict__ Wdec,
                        const float* __restrict__ bdec, const float* __restrict__ benc,
                        const float* __restrict__ Wbeta, const float* __restrict__ bbeta,
                        float* __restrict__ att2c, float* __restrict__ gate) {
    const int b = blockIdx.x, t = threadIdx.x;   // 256 threads
    __shared__ float hs[DEC_];
    __shared__ float pr[4];
    hs[t]       = h[(size_t)b*DEC_ + t];
    hs[t + 256] = h[(size_t)b*DEC_ + t + 256];
    __syncthreads();
    float a0 = 0.f, a1 = 0.f;
    for (int k = 0; k < DEC_; ++k) {
        float hk = hs[k];
        a0 = fmaf(hk, Wdec[(size_t)k*ATT_ + t],       a0);
        a1 = fmaf(hk, Wdec[(size_t)k*ATT_ + t + 256], a1);
    }
    att2c[(size_t)b*ATT_ + t]       = a0 + bdec[t]       + benc[t];
    att2c[(size_t)b*ATT_ + t + 256] = a1 + bdec[t + 256] + benc[t + 256];
    float p = hs[t]*Wbeta[t] + hs[t+256]*Wbeta[t+256];
#pragma unroll
    for (int mask = 32; mask; mask >>= 1) p += __shfl_xor(p, mask, 64);
    if ((t & 63) == 0) pr[t >> 6] = p;
    __syncthreads();
    if (t == 0) gate[b] = 1.f / (1.f + __expf(-(pr[0]+pr[1]+pr[2]+pr[3] + bbeta[0])));
}

// ---------- K1: att[m] = sum_n relu(x[m]@W_enc[:,n] + att2c[b(m)][n]) * W_full[n] ----------
// 256 threads = 4 waves. Block tile 64(M) x 512(N), BK=32, double-buffered LDS, one barrier/iter.
// Wave tile 64x128: acc[2][4] of 32x32x16 -> 16 MFMAs per K-iter per wave.
// LDS chunk-swizzle: chunk(r,kc) = r*4 + (kc ^ ((r>>1)&3)); 16B chunks. Conflict-balanced for
// gl_lds writes (lane-linear), ds_write_b128 of A, and strided frag reads (verified: 8 distinct
// addrs per bank-quad per b128 op = minimum phases).
__global__ __launch_bounds__(256, 2) void k_gemm(
        const float* __restrict__ x, const unsigned short* __restrict__ WT,
        const float* __restrict__ att2c, const float* __restrict__ Wfull,
        float* __restrict__ att) {
    __shared__ alignas(16) unsigned short Ab[2][64*32];    // 4 KB each
    __shared__ alignas(16) unsigned short Bb[2][512*32];   // 32 KB each
    __shared__ float att_ws[4][64];

    const int tid   = threadIdx.x;
    const int wave  = tid >> 6;
    const int lane  = tid & 63;
    const int lane31 = lane & 31;
    const int laneh  = lane >> 5;
    const int m0 = blockIdx.x * 64;

    f32x16 acc[2][4];
#pragma unroll
    for (int i = 0; i < 2; ++i)
#pragma unroll
        for (int j = 0; j < 4; ++j)
#pragma unroll
            for (int r = 0; r < 16; ++r) acc[i][j][r] = 0.f;

    // B staging: 8 gl_lds (1KB each) per wave per iter; per-lane source offset precomputed.
    int boff[8];
#pragma unroll
    for (int j = 0; j < 8; ++j) {
        int c  = (wave*8 + j)*64 + lane;
        int n  = c >> 2;
        int kc = (c & 3) ^ ((n >> 1) & 3);
        boff[j] = n*ENC_ + kc*8;
    }
    // A staging: thread -> (row ar, 8-float k-group g); one b128 ds_write per thread per iter.
    const int ar = tid >> 2, g = tid & 3;
    const int achunk = ar*4 + (g ^ ((ar >> 1) & 3));
    const float* xrow = x + (size_t)(m0 + ar)*ENC_ + g*8;

    // ---- prologue: stage k0=0 into buffer 0 ----
#pragma unroll
    for (int j = 0; j < 8; ++j)
        gl_lds16(WT + boff[j], (void*)&Bb[0][(wave*8 + j)*512]);
    float4 pa = *(const float4*)(xrow);
    float4 pb = *(const float4*)(xrow + 4);
    {
        short8 w;
        w[0] = f2bf(pa.x); w[1] = f2bf(pa.y); w[2] = f2bf(pa.z); w[3] = f2bf(pa.w);
        w[4] = f2bf(pb.x); w[5] = f2bf(pb.y); w[6] = f2bf(pb.z); w[7] = f2bf(pb.w);
        *(short8*)&Ab[0][achunk*8] = w;
    }

    for (int k0 = 0; k0 < ENC_; k0 += 32) {
        const int cur = (k0 >> 5) & 1, nxt = cur ^ 1;
        __syncthreads();                      // buffer `cur` staging complete
        const bool more = (k0 + 32) < ENC_;
        if (more) {
            // prefetch next B straight to LDS (DMA, drains at NEXT barrier)
#pragma unroll
            for (int j = 0; j < 8; ++j)
                gl_lds16(WT + boff[j] + (k0 + 32), (void*)&Bb[nxt][(wave*8 + j)*512]);
            // prefetch next A into registers (vmcnt wait deferred past compute)
            pa = *(const float4*)(xrow + k0 + 32);
            pb = *(const float4*)(xrow + k0 + 36);
        }
#pragma unroll
        for (int ks = 0; ks < 2; ++ks) {
            short8 a[2], bf[4];
#pragma unroll
            for (int mi = 0; mi < 2; ++mi) {
                int m  = mi*32 + lane31;
                int ch = m*4 + ((ks*2 + laneh) ^ ((m >> 1) & 3));
                a[mi] = *(const short8*)&Ab[cur][ch*8];
            }
#pragma unroll
            for (int ni = 0; ni < 4; ++ni) {
                int n  = wave*128 + ni*32 + lane31;
                int ch = n*4 + ((ks*2 + laneh) ^ ((n >> 1) & 3));
                bf[ni] = *(const short8*)&Bb[cur][ch*8];
            }
#pragma unroll
            for (int mi = 0; mi < 2; ++mi)
#pragma unroll
                for (int ni = 0; ni < 4; ++ni)
                    acc[mi][ni] = __builtin_amdgcn_mfma_f32_32x32x16_bf16(
                                      a[mi], bf[ni], acc[mi][ni], 0, 0, 0);
        }
        if (more) {
            // convert + write next A after compute (global latency hidden under MFMAs)
            short8 w;
            w[0] = f2bf(pa.x); w[1] = f2bf(pa.y); w[2] = f2bf(pa.z); w[3] = f2bf(pa.w);
            w[4] = f2bf(pb.x); w[5] = f2bf(pb.y); w[6] = f2bf(pb.z); w[7] = f2bf(pb.w);
            *(short8*)&Ab[nxt][achunk*8] = w;
        }
    }

    // ---- epilogue: relu(acc + att2c[b][n]) * Wfull[n], reduce over n, write att[m] ----
    // Bb[0]'s last read was iter 62; every wave passed iter-63's barrier after that -> safe to
    // write epi (first 6KB of Bb[0]) without an extra barrier.
    float* epi = (float*)&Bb[0][0];  // [0..511]=Wfull, [512..1023]=att2c[b0], [1024..1535]=att2c[b1]
    {
        const int b0i = m0 / L_;
        const int b1i = (m0 + 63) / L_;
        epi[tid]        = Wfull[tid];
        epi[256 + tid]  = Wfull[256 + tid];
        epi[512 + tid]  = att2c[(size_t)b0i*ATT_ + tid];
        epi[768 + tid]  = att2c[(size_t)b0i*ATT_ + 256 + tid];
        epi[1024 + tid] = att2c[(size_t)b1i*ATT_ + tid];
        epi[1280 + tid] = att2c[(size_t)b1i*ATT_ + 256 + tid];
    }
    __syncthreads();
    const int split = (m0 / L_ + 1) * L_;   // first global row of batch b1
#pragma unroll
    for (int mi = 0; mi < 2; ++mi) {
#pragma unroll
        for (int reg = 0; reg < 16; ++reg) {
            int r32  = (reg & 3) + 8*(reg >> 2) + 4*laneh;   // verified C/D map (m74/m101)
            int mloc = mi*32 + r32;
            int off  = (m0 + mloc >= split) ? 1024 : 512;
            float v = 0.f;
#pragma unroll
            for (int ni = 0; ni < 4; ++ni) {
                int n = wave*128 + ni*32 + lane31;
                float tv = acc[mi][ni][reg] + epi[off + n];
                v = fmaf(fmaxf(tv, 0.f), epi[n], v);
            }
#pragma unroll
            for (int mask = 16; mask; mask >>= 1) v += __shfl_xor(v, mask, 64);
            if (lane31 == 0) att_ws[wave][mloc] = v;
        }
    }
    __syncthreads();
    if (tid < 64)
        att[m0 + tid] = att_ws[0][tid] + att_ws[1][tid] + att_ws[2][tid] + att_ws[3][tid];
}

// ---------- K2: softmax over L, z = alpha@x[b], out0 = gate*z, out1 = alpha ----------
// grid (B, 2): each block handles 1024 of 2048 ENC cols -> 512 blocks = 2/CU for latency hiding.
__global__ __launch_bounds__(256) void k_softz(
        const float* __restrict__ att, const float* __restrict__ x,
        const float* __restrict__ gate, float* __restrict__ out) {
    const int b = blockIdx.x, s = blockIdx.y, t = threadIdx.x;   // 256 threads
    __shared__ float sa[L_];
    __shared__ float red[8];
    const int wid = t >> 6, lane = t & 63;
    float v = (t < L_) ? att[b*L_ + t] : -1e30f;
    float m = v;
#pragma unroll
    for (int mask = 32; mask; mask >>= 1) m = fmaxf(m, __shfl_xor(m, mask, 64));
    if (lane == 0) red[wid] = m;
    __syncthreads();
    m = fmaxf(fmaxf(red[0], red[1]), fmaxf(red[2], red[3]));
    float e = (t < L_) ? __expf(v - m) : 0.f;
    float sum = e;
#pragma unroll
    for (int mask = 32; mask; mask >>= 1) sum += __shfl_xor(sum, mask, 64);
    if (lane == 0) red[4 + wid] = sum;
    __syncthreads();
    sum = red[4] + red[5] + red[6] + red[7];
    float alpha = e / sum;
    if (t < L_) {
        sa[t] = alpha;
        if (s == 0) out[(size_t)B_*ENC_ + (size_t)b*L_ + t] = alpha;
    }
    __syncthreads();
    const float* xb = x + (size_t)b*L_*ENC_ + s*1024 + t*4;
    float4 z = {0.f, 0.f, 0.f, 0.f};
#pragma unroll 7
    for (int l = 0; l < L_; ++l) {
        float a = sa[l];
        float4 u = *(const float4*)(xb + (size_t)l*ENC_);
        z.x = fmaf(a, u.x, z.x); z.y = fmaf(a, u.y, z.y);
        z.z = fmaf(a, u.z, z.z); z.w = fmaf(a, u.w, z.w);
    }
    const float g = gate[b];
    float4 o; o.x = g*z.x; o.y = g*z.y; o.z = g*z.z; o.w = g*z.w;
    *(float4*)(out + (size_t)b*ENC_ + s*1024 + t*4) = o;
}

extern "C" void kernel_launch(void* const* d_in, const int* in_sizes, int n_in,
                              void* d_out, int out_size, void* d_ws, size_t ws_size,
                              hipStream_t stream) {
    const float* x      = (const float*)d_in[0];
    const float* h      = (const float*)d_in[1];
    const float* W_enc  = (const float*)d_in[2];
    const float* b_enc  = (const float*)d_in[3];
    const float* W_dec  = (const float*)d_in[4];
    const float* b_dec  = (const float*)d_in[5];
    const float* W_full = (const float*)d_in[6];
    // d_in[7] = b_full: softmax is shift-invariant -> unused
    const float* W_beta = (const float*)d_in[8];
    const float* b_beta = (const float*)d_in[9];
    float* out = (float*)d_out;

    char* ws = (char*)d_ws;
    unsigned short* WT = (unsigned short*)ws;                              // 2 MB
    float* att2c  = (float*)(ws + 2*1024*1024);                            // 512 KB
    float* gate   = (float*)(ws + 2*1024*1024 + 512*1024);                 // 1 KB
    float* attbuf = (float*)(ws + 2*1024*1024 + 512*1024 + 1024);          // 200 KB

    k_transpose<<<dim3(ENC_/32, ATT_/32), 256, 0, stream>>>(W_enc, WT);
    k_prep2   <<<B_, 256, 0, stream>>>(h, W_dec, b_dec, b_enc, W_beta, b_beta, att2c, gate);
    k_gemm    <<<M_TOT/64, 256, 0, stream>>>(x, WT, att2c, W_full, attbuf);
    k_softz   <<<dim3(B_, 2), 256, 0, stream>>>(attbuf, x, gate, out);
}